// Round 4
// baseline (241.992 us; speedup 1.0000x reference)
//
#include <hip/hip_runtime.h>
#include <hip/hip_bf16.h>
#include <math.h>

// Problem constants (reference: B=64, T=2048, D=256)
#define PB 64
#define PT 2048
#define PD 256
#define PM (PB * PT)
#define SBM 64
#define NTILES (PM / SBM)   // 2048 score tiles
#define TPB (PT / SBM)      // 32 tiles per batch row

typedef __bf16 bf16x8 __attribute__((ext_vector_type(8)));
typedef short  s16x8  __attribute__((ext_vector_type(8)));
typedef float  f32x4  __attribute__((ext_vector_type(4)));

__device__ __forceinline__ short rne_bf16(float x) {
    unsigned u = __builtin_bit_cast(unsigned, x);
    return (short)((u + 0x7fffu + ((u >> 16) & 1u)) >> 16);
}

// split fp32 -> hi (truncated bf16) + lo (RNE bf16 of remainder); hi+lo ~ 2^-17 accurate
__device__ __forceinline__ void split_bf16(float x, short& hi, short& lo) {
    unsigned u = __builtin_bit_cast(unsigned, x);
    hi = (short)(u >> 16);
    float hf = __builtin_bit_cast(float, u & 0xffff0000u);
    lo = rne_bf16(x - hf);
}

// ---------------- Kernel P: pack W into hi/lo bf16 B-fragment order --------
// B[k][e] = W[e][k]. mfma_f32_16x16x32_bf16: lane l holds B[k=(l>>4)*8+j][n=l&15].
// flat = ((nt*8 + kt)*64 + quad*16 + n_loc)*8 + j
__global__ __launch_bounds__(256) void prep_kernel(
    const float* __restrict__ W, short* __restrict__ Whi, short* __restrict__ Wlo)
{
    const int idx = blockIdx.x * 256 + threadIdx.x;   // = e*256 + k
    const int e = idx >> 8;
    const int k = idx & 255;
    short h, l;
    split_bf16(W[idx], h, l);
    const int flat = (((e >> 4) * 8 + (k >> 5)) * 64 + ((k & 31) >> 3) * 16 + (e & 15)) * 8 + (k & 7);
    Whi[flat] = h;
    Wlo[flat] = l;
}

// ---------------- Fused persistent kernel: weight-stationary ---------------
// 256 blocks (1/CU) x 512 threads (8 waves). Each wave owns a 32-col strip of
// W: B-fragments (hi+lo, all 8 k-tiles) live in 128 VGPRs for the whole
// kernel -> zero B traffic in steady state. STATIC tile schedule (no atomics;
// deterministic under rocprof replay): block k, step i handles
//   tile = (k&63)*32 + i*4 + (k>>6)
// — a bijection onto [0,2048) that gives each block one batch and 8 positions
// spread stride-4 across the masked tail (balances the masked-tile skip).
// Per tile: stage xs->bf16 A-frags in LDS | 128 MFMA/wave | tanh+attn-dot |
// per-tile softmax stats (flash) | weighted partial moments (xs L2-hot).
__global__ __launch_bounds__(512, 2) void score_kernel(
    const float* __restrict__ xs, const short* __restrict__ Whi,
    const short* __restrict__ Wlo, const float* __restrict__ bias,
    const float* __restrict__ attn, const int* __restrict__ mask,
    float* __restrict__ stats, float* __restrict__ part)
{
    // A-fragment-packed LDS: [mt(4)][kt(8)][lane(64)][j(8)] shorts, XOR-swizzled.
    // Reused as float4 reduction scratch in the moment epilogue (dead after GEMM).
    __shared__ __align__(16) short Ah[4 * 8 * 64 * 8];    // 32 KiB
    __shared__ float sred[8][64];
    __shared__ float lw[64];

    const int tid  = threadIdx.x;
    const int lane = tid & 63;
    const int w    = tid >> 6;        // wave 0..7
    const int quad = lane >> 4;
    const int nl   = lane & 15;
    const int blk  = blockIdx.x;

    // ---- load this wave's B strip (cols w*32 .. w*32+31) into registers ----
    bf16x8 Bh[2][8], Bl[2][8];
#pragma unroll
    for (int n = 0; n < 2; ++n) {
#pragma unroll
        for (int kt = 0; kt < 8; ++kt) {
            const int nt   = w * 2 + n;
            const int bidx = ((nt * 8 + kt) * 64 + lane) * 8;
            Bh[n][kt] = *(const bf16x8*)&Whi[bidx];
            Bl[n][kt] = *(const bf16x8*)&Wlo[bidx];
        }
    }
    float bv[2], av[2];
#pragma unroll
    for (int n = 0; n < 2; ++n) {
        const int col = w * 32 + n * 16 + nl;
        bv[n] = bias[col];
        av[n] = attn[col];
    }

    for (int i = 0; i < 8; ++i) {
        const int tile = (blk & 63) * 32 + i * 4 + (blk >> 6);   // block-uniform
        const int bm   = tile * SBM;

        // ---- early exit: fully-masked tile contributes zero weight ----
        // mask values identical across waves -> ballot is block-uniform.
        const int mv = mask[bm + lane];
        if (__ballot(mv != 0) == 0ull) {
            if (tid == 0) { stats[tile * 2] = -INFINITY; stats[tile * 2 + 1] = 0.f; }
            continue;
        }

        __syncthreads();   // previous tile's rmu/rm2 readers done before Ah overwrite

        // ---- stage xs tile as RNE bf16 in A-fragment order ----
#pragma unroll
        for (int p = 0; p < 4; ++p) {
            const int r  = p * 16 + (tid >> 5);
            const int kb = tid & 31;                       // 8-elem k-block
            const float4 a0 = *(const float4*)&xs[(bm + r) * PD + kb * 8];
            const float4 a1 = *(const float4*)&xs[(bm + r) * PD + kb * 8 + 4];
            const float f[8] = {a0.x, a0.y, a0.z, a0.w, a1.x, a1.y, a1.z, a1.w};
            s16x8 h;
#pragma unroll
            for (int j = 0; j < 8; ++j) h[j] = rne_bf16(f[j]);
            const int mt = r >> 4, m_loc = r & 15;
            const int kt = kb >> 2, qd = kb & 3;
            const int msw = m_loc ^ (kb & 7);              // bank swizzle
            *(s16x8*)&Ah[(((mt * 8 + kt) * 64) + qd * 16 + msw) * 8] = h;
        }
        __syncthreads();

        // ---- MFMA: 4 m-tiles x 2 n-tiles, hi+lo passes, K=256 ----
        f32x4 acc[4][2] = {};
#pragma unroll
        for (int kt = 0; kt < 8; ++kt) {
            s16x8 ah[4];
            const int msw = nl ^ ((kt * 4 + quad) & 7);
#pragma unroll
            for (int m = 0; m < 4; ++m)
                ah[m] = *(const s16x8*)&Ah[((m * 8 + kt) * 64 + quad * 16 + msw) * 8];
#pragma unroll
            for (int m = 0; m < 4; ++m) {
                const bf16x8 ahm = __builtin_bit_cast(bf16x8, ah[m]);
#pragma unroll
                for (int n = 0; n < 2; ++n) {
                    acc[m][n] = __builtin_amdgcn_mfma_f32_16x16x32_bf16(ahm, Bh[n][kt], acc[m][n], 0, 0, 0);
                    acc[m][n] = __builtin_amdgcn_mfma_f32_16x16x32_bf16(ahm, Bl[n][kt], acc[m][n], 0, 0, 0);
                }
            }
        }

        // ---- epilogue: +bias, tanh, dot attn over this wave's 32 cols ----
#pragma unroll
        for (int m = 0; m < 4; ++m) {
            float rs[4] = {0.f, 0.f, 0.f, 0.f};
#pragma unroll
            for (int n = 0; n < 2; ++n) {
#pragma unroll
                for (int r = 0; r < 4; ++r) {
                    const float u  = acc[m][n][r] + bv[n];
                    const float e2 = __expf(2.f * u);                    // inf ok -> th=1
                    const float th = 1.f - 2.f * __builtin_amdgcn_rcpf(e2 + 1.f);
                    rs[r] = fmaf(th, av[n], rs[r]);
                }
            }
#pragma unroll
            for (int off = 1; off < 16; off <<= 1) {
#pragma unroll
                for (int r = 0; r < 4; ++r) rs[r] += __shfl_xor(rs[r], off);
            }
            if (nl == 0) {
#pragma unroll
                for (int r = 0; r < 4; ++r) sred[w][m * 16 + quad * 4 + r] = rs[r];
            }
        }
        __syncthreads();

        // ---- per-tile masked softmax stats (wave 0 only) ----
        if (tid < 64) {
            float s = sred[0][tid] + sred[1][tid] + sred[2][tid] + sred[3][tid]
                    + sred[4][tid] + sred[5][tid] + sred[6][tid] + sred[7][tid];
            const bool vld = (mv != 0);                    // mv == mask[bm+tid] here
            s = vld ? s : -INFINITY;
            float mx = s;
#pragma unroll
            for (int off = 1; off < 64; off <<= 1) mx = fmaxf(mx, __shfl_xor(mx, off));
            const float wt = vld ? __expf(s - mx) : 0.f;
            float zs = wt;
#pragma unroll
            for (int off = 1; off < 64; off <<= 1) zs += __shfl_xor(zs, off);
            lw[tid] = wt;
            if (tid == 0) { stats[tile * 2] = mx; stats[tile * 2 + 1] = zs; }
        }
        __syncthreads();

        // ---- weighted partial moments over the tile (xs from global, L2-hot) ----
        float4* rmu = (float4*)Ah;            // [8][64], aliases dead Ah (16 KiB used)
        float4* rm2 = rmu + 8 * 64;
        float4 mu = {0.f, 0.f, 0.f, 0.f};
        float4 m2 = {0.f, 0.f, 0.f, 0.f};
#pragma unroll
        for (int j = 0; j < 8; ++j) {
            const int r  = w * 8 + j;
            const float wv = lw[r];
            const float4 x = *(const float4*)&xs[(bm + r) * PD + lane * 4];
            mu.x = fmaf(wv, x.x, mu.x); mu.y = fmaf(wv, x.y, mu.y);
            mu.z = fmaf(wv, x.z, mu.z); mu.w = fmaf(wv, x.w, mu.w);
            m2.x = fmaf(wv * x.x, x.x, m2.x); m2.y = fmaf(wv * x.y, x.y, m2.y);
            m2.z = fmaf(wv * x.z, x.z, m2.z); m2.w = fmaf(wv * x.w, x.w, m2.w);
        }
        rmu[w * 64 + lane] = mu;
        rm2[w * 64 + lane] = m2;
        __syncthreads();

        if (tid < 64) {
            float4 smu = rmu[tid], sm2 = rm2[tid];
#pragma unroll
            for (int q = 1; q < 8; ++q) {
                const float4 a = rmu[q * 64 + tid], d = rm2[q * 64 + tid];
                smu.x += a.x; smu.y += a.y; smu.z += a.z; smu.w += a.w;
                sm2.x += d.x; sm2.y += d.y; sm2.z += d.z; sm2.w += d.w;
            }
            const int base = tile * 512;
            *(float4*)&part[base + tid * 4]       = smu;
            *(float4*)&part[base + 256 + tid * 4] = sm2;
        }
        // next iteration's pre-staging __syncthreads() protects Ah/lw reuse
    }
}

// ---------------- Final reduce: rescale tiles, normalize, finalize ---------
__global__ __launch_bounds__(256) void finalize_kernel(
    const float* __restrict__ stats, const float* __restrict__ part,
    float* __restrict__ out)
{
    const int b = blockIdx.x;
    const int d = threadIdx.x;

    float M = -INFINITY;
#pragma unroll
    for (int t = 0; t < TPB; ++t) M = fmaxf(M, stats[(b * TPB + t) * 2]);

    float Z = 0.f, m1 = 0.f, m2 = 0.f;
#pragma unroll 4
    for (int t = 0; t < TPB; ++t) {
        const int g = b * TPB + t;
        const float zt = stats[g * 2 + 1];
        if (zt > 0.f) {                                 // uniform branch per block
            const float f = __expf(stats[g * 2] - M);
            Z  = fmaf(zt, f, Z);
            m1 = fmaf(part[g * 512 + d],       f, m1);
            m2 = fmaf(part[g * 512 + 256 + d], f, m2);
        }
    }
    const float inv = 1.f / Z;
    m1 *= inv;
    m2 *= inv;
    const float var = fmaxf(m2 - m1 * m1, 1e-5f);
    out[b * 512 + d]       = m1;
    out[b * 512 + 256 + d] = sqrtf(var);
}

extern "C" void kernel_launch(void* const* d_in, const int* in_sizes, int n_in,
                              void* d_out, int out_size, void* d_ws, size_t ws_size,
                              hipStream_t stream) {
    const float* xs   = (const float*)d_in[0];
    const int*   mask = (const int*)d_in[1];
    // d_in[2] = mask2, unused
    const float* W    = (const float*)d_in[3];
    const float* bias = (const float*)d_in[4];
    const float* attn = (const float*)d_in[5];
    float* out = (float*)d_out;

    float* stats = (float*)d_ws;                     // NTILES*2 floats
    float* part  = stats + NTILES * 2;               // NTILES*512 floats (4 MB)
    short* Whi   = (short*)(part + NTILES * 512);    // 65536 shorts
    short* Wlo   = Whi + PD * PD;                    // 65536 shorts

    prep_kernel<<<PD * PD / 256, 256, 0, stream>>>(W, Whi, Wlo);
    score_kernel<<<256, 512, 0, stream>>>(xs, Whi, Wlo, bias, attn, mask, stats, part);
    finalize_kernel<<<PB, 256, 0, stream>>>(stats, part, out);
}

// Round 5
// 230.928 us; speedup vs baseline: 1.0479x; 1.0479x over previous
//
#include <hip/hip_runtime.h>
#include <hip/hip_bf16.h>
#include <math.h>

// Problem constants (reference: B=64, T=2048, D=256)
#define PB 64
#define PT 2048
#define PD 256
#define PM (PB * PT)
#define SBM 128
#define NTILES (PM / SBM)   // 1024 score tiles
#define TPB (PT / SBM)      // 16 tiles per batch row

typedef __bf16 bf16x8 __attribute__((ext_vector_type(8)));
typedef short  s16x8  __attribute__((ext_vector_type(8)));
typedef float  f32x4  __attribute__((ext_vector_type(4)));

__device__ __forceinline__ short rne_bf16(float x) {
    unsigned u = __builtin_bit_cast(unsigned, x);
    return (short)((u + 0x7fffu + ((u >> 16) & 1u)) >> 16);
}

// split fp32 -> hi (truncated bf16) + lo (RNE bf16 of remainder); hi+lo ~ 2^-17 accurate
__device__ __forceinline__ void split_bf16(float x, short& hi, short& lo) {
    unsigned u = __builtin_bit_cast(unsigned, x);
    hi = (short)(u >> 16);
    float hf = __builtin_bit_cast(float, u & 0xffff0000u);
    lo = rne_bf16(x - hf);
}

// ---------------- Kernel P: pack W into hi/lo bf16 B-fragment order --------
// B[k][e] = W[e][k]. mfma_f32_16x16x32_bf16: lane l holds B[k=(l>>4)*8+j][n=l&15].
// flat = ((nt*8 + kt)*64 + quad*16 + n_loc)*8 + j
__global__ __launch_bounds__(256) void prep_kernel(
    const float* __restrict__ W, short* __restrict__ Whi, short* __restrict__ Wlo)
{
    const int idx = blockIdx.x * 256 + threadIdx.x;   // = e*256 + k
    const int e = idx >> 8;
    const int k = idx & 255;
    short h, l;
    split_bf16(W[idx], h, l);
    const int flat = (((e >> 4) * 8 + (k >> 5)) * 64 + ((k & 31) >> 3) * 16 + (e & 15)) * 8 + (k & 7);
    Whi[flat] = h;
    Wlo[flat] = l;
}

// ---------------- Fused kernel: 128-row tiles, one tile per block ----------
// 1024 blocks x 512 threads (8 waves, 2 blocks/CU -> 16 waves/CU). Each wave
// owns a 32-col strip; B hi/lo fragments are loaded from L2 inside the K-loop
// (weight-stationary-in-VGPR failed in R4: 128 B-regs can't stay resident).
// 128-row tile halves per-row B traffic vs 64-row and doubles MFMA:load ratio.
// Per tile: stage xs->bf16 A-frags in LDS | 256 MFMA/wave | tanh+attn-dot |
// per-tile softmax stats (flash) | weighted partial moments (xs L2-hot).
__global__ __launch_bounds__(512, 4) void score_kernel(
    const float* __restrict__ xs, const short* __restrict__ Whi,
    const short* __restrict__ Wlo, const float* __restrict__ bias,
    const float* __restrict__ attn, const int* __restrict__ mask,
    float* __restrict__ stats, float* __restrict__ part)
{
    // A-fragment-packed LDS: [mt(8)][kt(8)][lane(64)][j(8)] shorts, XOR-swizzled.
    // Reused as float4 reduction scratch in the moment epilogue (dead after GEMM).
    __shared__ __align__(16) short Ah[8 * 8 * 64 * 8];    // 64 KiB
    __shared__ float sred[8][128];                        // 4 KiB
    __shared__ float lw[128];
    __shared__ int vflag[8];

    const int tid  = threadIdx.x;
    const int lane = tid & 63;
    const int w    = tid >> 6;        // wave 0..7
    const int quad = lane >> 4;
    const int nl   = lane & 15;

    // blockIdx -> (batch, chunk): consecutive blocks spread across batches so
    // the resident set always has work; masked-tail chunks drain fast.
    const int blk   = blockIdx.x;
    const int tile  = (blk & 63) * TPB + (blk >> 6);
    const int bm    = tile * SBM;

    // ---- early exit: fully-masked tile contributes zero weight ----
    const int mv = mask[bm + (tid & 127)];     // each row read 4x across waves
    {
        const unsigned long long bal = __ballot(mv != 0);
        if (lane == 0) vflag[w] = (bal != 0ull) ? 1 : 0;
    }
    __syncthreads();
    const int any = vflag[0] | vflag[1] | vflag[2] | vflag[3]
                  | vflag[4] | vflag[5] | vflag[6] | vflag[7];
    if (!any) {
        if (tid == 0) { stats[tile * 2] = -INFINITY; stats[tile * 2 + 1] = 0.f; }
        return;
    }

    // ---- stage xs tile (128 x 256) as RNE bf16 in A-fragment order ----
#pragma unroll
    for (int p = 0; p < 8; ++p) {
        const int r  = p * 16 + (tid >> 5);            // 0..127
        const int kb = tid & 31;                       // 8-elem k-block
        const float4 a0 = *(const float4*)&xs[(bm + r) * PD + kb * 8];
        const float4 a1 = *(const float4*)&xs[(bm + r) * PD + kb * 8 + 4];
        const float f[8] = {a0.x, a0.y, a0.z, a0.w, a1.x, a1.y, a1.z, a1.w};
        s16x8 h;
#pragma unroll
        for (int j = 0; j < 8; ++j) h[j] = rne_bf16(f[j]);
        const int mt = r >> 4, m_loc = r & 15;
        const int kt = kb >> 2, qd = kb & 3;
        const int msw = m_loc ^ (kb & 7);              // bank swizzle
        *(s16x8*)&Ah[(((mt * 8 + kt) * 64) + qd * 16 + msw) * 8] = h;
    }
    __syncthreads();

    // ---- MFMA: 8 m-tiles x 2 n-tiles, hi+lo passes, K=256 ----
    // Two m-groups of 4 keep live VGPRs ~116 (acc 64 + bh/bl 16 + ah 16 + misc).
    f32x4 acc[8][2] = {};
#pragma unroll 2
    for (int kt = 0; kt < 8; ++kt) {
        bf16x8 bh[2], bl[2];
#pragma unroll
        for (int n = 0; n < 2; ++n) {
            const int nt   = w * 2 + n;
            const int bidx = ((nt * 8 + kt) * 64 + lane) * 8;
            bh[n] = *(const bf16x8*)&Whi[bidx];
            bl[n] = *(const bf16x8*)&Wlo[bidx];
        }
        const int msw = nl ^ ((kt * 4 + quad) & 7);
#pragma unroll
        for (int g = 0; g < 2; ++g) {
            s16x8 ah[4];
#pragma unroll
            for (int mm = 0; mm < 4; ++mm) {
                const int m = g * 4 + mm;
                ah[mm] = *(const s16x8*)&Ah[((m * 8 + kt) * 64 + quad * 16 + msw) * 8];
            }
#pragma unroll
            for (int mm = 0; mm < 4; ++mm) {
                const bf16x8 ahm = __builtin_bit_cast(bf16x8, ah[mm]);
#pragma unroll
                for (int n = 0; n < 2; ++n) {
                    acc[g * 4 + mm][n] = __builtin_amdgcn_mfma_f32_16x16x32_bf16(ahm, bh[n], acc[g * 4 + mm][n], 0, 0, 0);
                    acc[g * 4 + mm][n] = __builtin_amdgcn_mfma_f32_16x16x32_bf16(ahm, bl[n], acc[g * 4 + mm][n], 0, 0, 0);
                }
            }
        }
    }

    // ---- epilogue: +bias, tanh, dot attn over this wave's 32 cols ----
    float bv[2], av[2];
#pragma unroll
    for (int n = 0; n < 2; ++n) {
        const int col = w * 32 + n * 16 + nl;
        bv[n] = bias[col];
        av[n] = attn[col];
    }
#pragma unroll
    for (int m = 0; m < 8; ++m) {
        float rs[4] = {0.f, 0.f, 0.f, 0.f};
#pragma unroll
        for (int n = 0; n < 2; ++n) {
#pragma unroll
            for (int r = 0; r < 4; ++r) {
                const float u  = acc[m][n][r] + bv[n];
                const float e2 = __expf(2.f * u);                    // inf ok -> th=1
                const float th = 1.f - 2.f * __builtin_amdgcn_rcpf(e2 + 1.f);
                rs[r] = fmaf(th, av[n], rs[r]);
            }
        }
#pragma unroll
        for (int off = 1; off < 16; off <<= 1) {
#pragma unroll
            for (int r = 0; r < 4; ++r) rs[r] += __shfl_xor(rs[r], off);
        }
        if (nl == 0) {
#pragma unroll
            for (int r = 0; r < 4; ++r) sred[w][m * 16 + quad * 4 + r] = rs[r];
        }
    }
    __syncthreads();

    // ---- per-tile masked softmax stats (wave 0; 2 rows per lane) ----
    if (tid < 64) {
        float s0 = 0.f, s1 = 0.f;
#pragma unroll
        for (int q = 0; q < 8; ++q) { s0 += sred[q][tid]; s1 += sred[q][tid + 64]; }
        const bool v0 = (mask[bm + tid] != 0);
        const bool v1 = (mask[bm + tid + 64] != 0);
        s0 = v0 ? s0 : -INFINITY;
        s1 = v1 ? s1 : -INFINITY;
        float mx = fmaxf(s0, s1);
#pragma unroll
        for (int off = 1; off < 64; off <<= 1) mx = fmaxf(mx, __shfl_xor(mx, off));
        const float w0 = v0 ? __expf(s0 - mx) : 0.f;
        const float w1 = v1 ? __expf(s1 - mx) : 0.f;
        float zs = w0 + w1;
#pragma unroll
        for (int off = 1; off < 64; off <<= 1) zs += __shfl_xor(zs, off);
        lw[tid]      = w0;
        lw[tid + 64] = w1;
        if (tid == 0) { stats[tile * 2] = mx; stats[tile * 2 + 1] = zs; }
    }
    __syncthreads();

    // ---- weighted partial moments over the tile (xs from global, L2-hot) ----
    float4* rmu = (float4*)Ah;            // [8][64], aliases dead Ah (16 KiB used)
    float4* rm2 = rmu + 8 * 64;
    float4 mu = {0.f, 0.f, 0.f, 0.f};
    float4 m2 = {0.f, 0.f, 0.f, 0.f};
#pragma unroll
    for (int j = 0; j < 16; ++j) {
        const int r  = w * 16 + j;
        const float wv = lw[r];
        const float4 x = *(const float4*)&xs[(bm + r) * PD + lane * 4];
        mu.x = fmaf(wv, x.x, mu.x); mu.y = fmaf(wv, x.y, mu.y);
        mu.z = fmaf(wv, x.z, mu.z); mu.w = fmaf(wv, x.w, mu.w);
        m2.x = fmaf(wv * x.x, x.x, m2.x); m2.y = fmaf(wv * x.y, x.y, m2.y);
        m2.z = fmaf(wv * x.z, x.z, m2.z); m2.w = fmaf(wv * x.w, x.w, m2.w);
    }
    rmu[w * 64 + lane] = mu;
    rm2[w * 64 + lane] = m2;
    __syncthreads();

    if (tid < 64) {
        float4 smu = rmu[tid], sm2 = rm2[tid];
#pragma unroll
        for (int q = 1; q < 8; ++q) {
            const float4 a = rmu[q * 64 + tid], d = rm2[q * 64 + tid];
            smu.x += a.x; smu.y += a.y; smu.z += a.z; smu.w += a.w;
            sm2.x += d.x; sm2.y += d.y; sm2.z += d.z; sm2.w += d.w;
        }
        const int base = tile * 512;
        *(float4*)&part[base + tid * 4]       = smu;
        *(float4*)&part[base + 256 + tid * 4] = sm2;
    }
}

// ---------------- Final reduce: rescale tiles, normalize, finalize ---------
__global__ __launch_bounds__(256) void finalize_kernel(
    const float* __restrict__ stats, const float* __restrict__ part,
    float* __restrict__ out)
{
    const int b = blockIdx.x;
    const int d = threadIdx.x;

    float M = -INFINITY;
#pragma unroll
    for (int t = 0; t < TPB; ++t) M = fmaxf(M, stats[(b * TPB + t) * 2]);

    float Z = 0.f, m1 = 0.f, m2 = 0.f;
#pragma unroll 4
    for (int t = 0; t < TPB; ++t) {
        const int g = b * TPB + t;
        const float zt = stats[g * 2 + 1];
        if (zt > 0.f) {                                 // uniform branch per block
            const float f = __expf(stats[g * 2] - M);
            Z  = fmaf(zt, f, Z);
            m1 = fmaf(part[g * 512 + d],       f, m1);
            m2 = fmaf(part[g * 512 + 256 + d], f, m2);
        }
    }
    const float inv = 1.f / Z;
    m1 *= inv;
    m2 *= inv;
    const float var = fmaxf(m2 - m1 * m1, 1e-5f);
    out[b * 512 + d]       = m1;
    out[b * 512 + 256 + d] = sqrtf(var);
}

extern "C" void kernel_launch(void* const* d_in, const int* in_sizes, int n_in,
                              void* d_out, int out_size, void* d_ws, size_t ws_size,
                              hipStream_t stream) {
    const float* xs   = (const float*)d_in[0];
    const int*   mask = (const int*)d_in[1];
    // d_in[2] = mask2, unused
    const float* W    = (const float*)d_in[3];
    const float* bias = (const float*)d_in[4];
    const float* attn = (const float*)d_in[5];
    float* out = (float*)d_out;

    float* stats = (float*)d_ws;                     // NTILES*2 floats
    float* part  = stats + NTILES * 2;               // NTILES*512 floats (2 MB)
    short* Whi   = (short*)(part + NTILES * 512);    // 65536 shorts
    short* Wlo   = Whi + PD * PD;                    // 65536 shorts

    prep_kernel<<<PD * PD / 256, 256, 0, stream>>>(W, Whi, Wlo);
    score_kernel<<<NTILES, 512, 0, stream>>>(xs, Whi, Wlo, bias, attn, mask, stats, part);
    finalize_kernel<<<PB, 256, 0, stream>>>(stats, part, out);
}